// Round 6
// baseline (483.809 us; speedup 1.0000x reference)
//
#include <hip/hip_runtime.h>

#define NN 100000
#define NE 1600000
#define DIN 128
#define HD 64
#define NBUK 1563          // ceil(100000/64) buckets of 64 nodes
#define EPB 2560           // edges per block in bucket build
#define NBLK 625           // 625 * 2560 = 1,600,000

__device__ __forceinline__ unsigned short f2bf(float f) {
    unsigned int u = __float_as_uint(f);
    u += 0x7fff + ((u >> 16) & 1);     // round-to-nearest-even
    return (unsigned short)(u >> 16);
}
__device__ __forceinline__ float bf2f(unsigned int lo16) {
    return __uint_as_float(lo16 << 16);
}

// ---------------- bucket histogram (LDS-aggregated) ----------------
__global__ __launch_bounds__(256) void k_bhist(const int* __restrict__ dst, int* __restrict__ bcount) {
    __shared__ int lh[NBUK];
    int tid = threadIdx.x;
    for (int b = tid; b < NBUK; b += 256) lh[b] = 0;
    __syncthreads();
    int base = blockIdx.x * EPB + tid;
#pragma unroll
    for (int i = 0; i < EPB / 256; ++i)
        atomicAdd(&lh[dst[base + i * 256] >> 6], 1);
    __syncthreads();
    for (int b = tid; b < NBUK; b += 256) {
        int c = lh[b];
        if (c) atomicAdd(&bcount[b], c);
    }
}

// ---------------- scan buckets -> bstart[0..NBUK], bcursor copy ----------------
__global__ __launch_bounds__(256) void k_bscan(const int* __restrict__ bcount, int* __restrict__ bstart,
                                               int* __restrict__ bcursor) {
    __shared__ int ts[256];
    int t = threadIdx.x;
    int vals[7];
    int s = 0;
#pragma unroll
    for (int j = 0; j < 7; ++j) {
        int ix = t * 7 + j;
        vals[j] = (ix < NBUK) ? bcount[ix] : 0;
        s += vals[j];
    }
    ts[t] = s;
    __syncthreads();
    for (int o = 1; o < 256; o <<= 1) {
        int xv = 0;
        if (t >= o) xv = ts[t - o];
        __syncthreads();
        ts[t] += xv;
        __syncthreads();
    }
    int run = (t == 0) ? 0 : ts[t - 1];
#pragma unroll
    for (int j = 0; j < 7; ++j) {
        int ix = t * 7 + j;
        if (ix <= NBUK) {
            bstart[ix] = run;
            if (ix < NBUK) bcursor[ix] = run;
        }
        run += vals[j];
    }
}

// ---------------- bucket scatter: block-aggregated reservation, L2-merged writes ----------------
// ep entry: { src | (row_in_bucket << 17),  0.9f * edge_weight }
__global__ __launch_bounds__(256) void k_bscatter(const int* __restrict__ src, const int* __restrict__ dst,
                                                  const float* __restrict__ ew, int* __restrict__ bcursor,
                                                  int2* __restrict__ ep) {
    __shared__ int lh[NBUK];
    __shared__ int gb[NBUK];
    int tid = threadIdx.x;
    for (int b = tid; b < NBUK; b += 256) lh[b] = 0;
    __syncthreads();
    int base = blockIdx.x * EPB + tid;
#pragma unroll
    for (int i = 0; i < EPB / 256; ++i)
        atomicAdd(&lh[dst[base + i * 256] >> 6], 1);
    __syncthreads();
    for (int b = tid; b < NBUK; b += 256) {
        int c = lh[b];
        if (c) gb[b] = atomicAdd(&bcursor[b], c);
    }
    __syncthreads();
#pragma unroll
    for (int i = 0; i < EPB / 256; ++i) {
        int e = base + i * 256;
        int d = dst[e];
        int pos = atomicAdd(&gb[d >> 6], 1);
        ep[pos] = make_int2(src[e] | ((d & 63) << 17), __float_as_int(0.9f * ew[e]));
    }
}

// ---------------- per-bucket node sort: ep -> ep2 (CSR order) + row_ptr ----------------
__global__ __launch_bounds__(256) void k_bsort(const int2* __restrict__ ep, const int* __restrict__ bstart,
                                               int2* __restrict__ ep2, int* __restrict__ row_ptr) {
    __shared__ int cnt64[64];
    __shared__ int cur64[64];
    int b = blockIdx.x;
    int tid = threadIdx.x;
    if (tid < 64) cnt64[tid] = 0;
    __syncthreads();
    int e0 = bstart[b], e1 = bstart[b + 1];
    for (int e = e0 + tid; e < e1; e += 256)
        atomicAdd(&cnt64[(ep[e].x >> 17) & 63], 1);
    __syncthreads();
    if (tid == 0) {
        int run = e0;
        for (int r = 0; r < 64; ++r) {
            int node = b * 64 + r;
            cur64[r] = run;
            if (node <= NN) row_ptr[node] = run;
            run += cnt64[r];
        }
    }
    __syncthreads();
    for (int e = e0 + tid; e < e1; e += 256) {
        int2 m = ep[e];
        int r = (m.x >> 17) & 63;
        int pos = atomicAdd(&cur64[r], 1);
        ep2[pos] = make_int2(m.x & 0x1FFFF, m.y);
    }
    if (b == NBUK - 1 && tid == 0) row_ptr[NN] = e1;
}

// ---------------- M_l = theta*W_l + (1-theta)*I ----------------
__global__ __launch_bounds__(256) void k_mprep(const float* __restrict__ gw, float* __restrict__ M, float4 th) {
    int idx = blockIdx.x * 256 + threadIdx.x;   // < 4*64*64
    int l = idx >> 12;
    int k = (idx >> 6) & 63;
    int c = idx & 63;
    float theta = (l == 0) ? th.x : (l == 1) ? th.y : (l == 2) ? th.z : th.w;
    float m = theta * gw[idx];
    if (k == c) m += (1.f - theta);
    M[idx] = m;
}

// ---------------- fused proj + MLP branch: one pass over x, weights from L1 ----------------
// h0b = bf16(x @ proj_w + proj_b); out = 0.5*(mlp3(x) + b3)
// LDS = As (16.6 KB) + red (8.7 KB) only -> ~6 blocks/CU
__global__ __launch_bounds__(256) void k_projmlp(const float* __restrict__ x,
        const float* __restrict__ pW, const float* __restrict__ pb,
        const float* __restrict__ W1, const float* __restrict__ b1,
        const float* __restrict__ g1, const float* __restrict__ be1,
        const float* __restrict__ W2, const float* __restrict__ b2,
        const float* __restrict__ g2, const float* __restrict__ be2,
        const float* __restrict__ w3, const float* __restrict__ b3,
        unsigned short* __restrict__ h0b, float* __restrict__ out) {
    __shared__ float As[64 * 65];
    __shared__ float2 red[64 * 17];
    int tid = threadIdx.x;
    int cc = tid & 15, nc = tid >> 4;
    int tile0 = blockIdx.x * 64;
    float accP[4][4] = {{0.f}};
    float accM[4][4] = {{0.f}};
    for (int kc = 0; kc < DIN; kc += 64) {
        __syncthreads();
#pragma unroll
        for (int it = 0; it < 4; ++it) {
            int idx = tid + it * 256;
            int r = idx >> 4, q = (idx & 15) * 4;
            int gn = tile0 + r;
            float4 v = make_float4(0.f, 0.f, 0.f, 0.f);
            if (gn < NN) v = *(const float4*)&x[(size_t)gn * DIN + kc + q];
            As[r * 65 + q + 0] = v.x; As[r * 65 + q + 1] = v.y;
            As[r * 65 + q + 2] = v.z; As[r * 65 + q + 3] = v.w;
        }
        __syncthreads();
#pragma unroll 4
        for (int k = 0; k < 64; ++k) {
            float4 bp = *(const float4*)&pW[(size_t)(kc + k) * 64 + cc * 4];
            float4 bm = *(const float4*)&W1[(size_t)(kc + k) * 64 + cc * 4];
            float a0 = As[(nc * 4 + 0) * 65 + k];
            float a1 = As[(nc * 4 + 1) * 65 + k];
            float a2 = As[(nc * 4 + 2) * 65 + k];
            float a3 = As[(nc * 4 + 3) * 65 + k];
            accP[0][0] += a0 * bp.x; accP[0][1] += a0 * bp.y; accP[0][2] += a0 * bp.z; accP[0][3] += a0 * bp.w;
            accP[1][0] += a1 * bp.x; accP[1][1] += a1 * bp.y; accP[1][2] += a1 * bp.z; accP[1][3] += a1 * bp.w;
            accP[2][0] += a2 * bp.x; accP[2][1] += a2 * bp.y; accP[2][2] += a2 * bp.z; accP[2][3] += a2 * bp.w;
            accP[3][0] += a3 * bp.x; accP[3][1] += a3 * bp.y; accP[3][2] += a3 * bp.z; accP[3][3] += a3 * bp.w;
            accM[0][0] += a0 * bm.x; accM[0][1] += a0 * bm.y; accM[0][2] += a0 * bm.z; accM[0][3] += a0 * bm.w;
            accM[1][0] += a1 * bm.x; accM[1][1] += a1 * bm.y; accM[1][2] += a1 * bm.z; accM[1][3] += a1 * bm.w;
            accM[2][0] += a2 * bm.x; accM[2][1] += a2 * bm.y; accM[2][2] += a2 * bm.z; accM[2][3] += a2 * bm.w;
            accM[3][0] += a3 * bm.x; accM[3][1] += a3 * bm.y; accM[3][2] += a3 * bm.z; accM[3][3] += a3 * bm.w;
        }
    }
    __syncthreads();   // k-loop reads of As done
    // proj epilogue -> h0b (bf16)
#pragma unroll
    for (int i = 0; i < 4; ++i) {
        int gn = tile0 + nc * 4 + i;
        if (gn < NN) {
            ushort4 ob;
            ob.x = f2bf(accP[i][0] + pb[cc * 4 + 0]);
            ob.y = f2bf(accP[i][1] + pb[cc * 4 + 1]);
            ob.z = f2bf(accP[i][2] + pb[cc * 4 + 2]);
            ob.w = f2bf(accP[i][3] + pb[cc * 4 + 3]);
            *(ushort4*)&h0b[(size_t)gn * 64 + cc * 4] = ob;
        }
    }
    // mlp stats1 (bias folded)
    float vals[4][4];
#pragma unroll
    for (int i = 0; i < 4; ++i) {
        float s = 0.f, q = 0.f;
#pragma unroll
        for (int j = 0; j < 4; ++j) {
            float v = accM[i][j] + b1[cc * 4 + j];
            vals[i][j] = v; s += v; q += v * v;
        }
        red[(nc * 4 + i) * 17 + cc] = make_float2(s, q);
    }
    __syncthreads();
    // LN1 + relu -> m1 into As
#pragma unroll
    for (int i = 0; i < 4; ++i) {
        int r = nc * 4 + i;
        float S = 0.f, Q = 0.f;
#pragma unroll
        for (int j = 0; j < 16; ++j) { float2 f = red[r * 17 + j]; S += f.x; Q += f.y; }
        float mu = S * (1.f / 64.f);
        float var = Q * (1.f / 64.f) - mu * mu;
        float rs = rsqrtf(var + 1e-5f);
#pragma unroll
        for (int j = 0; j < 4; ++j) {
            int c = cc * 4 + j;
            float m = (vals[i][j] - mu) * rs * g1[c] + be1[c];
            As[r * 65 + c] = fmaxf(m, 0.f);
        }
    }
    __syncthreads();
    // GEMM2: m1 @ W2 (W2 from L1 — 16 KB)
    float acc2[4][4] = {{0.f}};
#pragma unroll 8
    for (int k = 0; k < 64; ++k) {
        float4 b4 = *(const float4*)&W2[(size_t)k * 64 + cc * 4];
        float a0 = As[(nc * 4 + 0) * 65 + k];
        float a1 = As[(nc * 4 + 1) * 65 + k];
        float a2 = As[(nc * 4 + 2) * 65 + k];
        float a3 = As[(nc * 4 + 3) * 65 + k];
        acc2[0][0] += a0 * b4.x; acc2[0][1] += a0 * b4.y; acc2[0][2] += a0 * b4.z; acc2[0][3] += a0 * b4.w;
        acc2[1][0] += a1 * b4.x; acc2[1][1] += a1 * b4.y; acc2[1][2] += a1 * b4.z; acc2[1][3] += a1 * b4.w;
        acc2[2][0] += a2 * b4.x; acc2[2][1] += a2 * b4.y; acc2[2][2] += a2 * b4.z; acc2[2][3] += a2 * b4.w;
        acc2[3][0] += a3 * b4.x; acc2[3][1] += a3 * b4.y; acc2[3][2] += a3 * b4.z; acc2[3][3] += a3 * b4.w;
    }
    __syncthreads();
    // stats2
#pragma unroll
    for (int i = 0; i < 4; ++i) {
        float s = 0.f, q = 0.f;
#pragma unroll
        for (int j = 0; j < 4; ++j) {
            float v = acc2[i][j] + b2[cc * 4 + j];
            vals[i][j] = v; s += v; q += v * v;
        }
        red[(nc * 4 + i) * 17 + cc] = make_float2(s, q);
    }
    __syncthreads();
    // LN2 + relu + dot w3
    float part[4];
#pragma unroll
    for (int i = 0; i < 4; ++i) {
        int r = nc * 4 + i;
        float S = 0.f, Q = 0.f;
#pragma unroll
        for (int j = 0; j < 16; ++j) { float2 f = red[r * 17 + j]; S += f.x; Q += f.y; }
        float mu = S * (1.f / 64.f);
        float var = Q * (1.f / 64.f) - mu * mu;
        float rs = rsqrtf(var + 1e-5f);
        float p = 0.f;
#pragma unroll
        for (int j = 0; j < 4; ++j) {
            int c = cc * 4 + j;
            float m = fmaxf((vals[i][j] - mu) * rs * g2[c] + be2[c], 0.f);
            p += m * w3[c];
        }
        part[i] = p;
    }
    __syncthreads();
#pragma unroll
    for (int i = 0; i < 4; ++i) red[(nc * 4 + i) * 17 + cc] = make_float2(part[i], 0.f);
    __syncthreads();
    if (tid < 64) {
        float S = 0.f;
#pragma unroll
        for (int j = 0; j < 16; ++j) S += red[tid * 17 + j].x;
        int gn = tile0 + tid;
        if (gn < NN) out[gn] = 0.5f * (S + b3[0]);
    }
}

// ---------------- fused layer: CSR spmm (reg accum, 16 lanes/node) + GEMM(M from L1) + relu ----------------
__global__ __launch_bounds__(256) void k_layer(const int2* __restrict__ ep, const int* __restrict__ row_ptr,
                                               const unsigned short* __restrict__ hbin,   // bf16 h prev
                                               const unsigned short* __restrict__ h0b,    // bf16 h0
                                               const float* __restrict__ M,               // 64x64
                                               unsigned short* __restrict__ hbout) {      // bf16 h out
    __shared__ float As[64 * 65];
    int tid = threadIdx.x;
    int wid = tid >> 6, lane = tid & 63;
    int g = lane >> 4, hl = lane & 15;       // group g of 16 lanes; lane covers channels hl*4..hl*4+3
    int tile0 = blockIdx.x * 64;

    // spmm: wave covers 16 rows, 4 concurrent groups x 4-edge unroll
#pragma unroll 1
    for (int i = 0; i < 4; ++i) {
        int r = wid * 16 + i * 4 + g;
        int node = tile0 + r;
        float a0 = 0.f, a1 = 0.f, a2 = 0.f, a3 = 0.f;
        if (node < NN) {
            int e = row_ptr[node], e1 = row_ptr[node + 1];
            for (; e + 4 <= e1; e += 4) {
                int2 m0 = ep[e], m1 = ep[e + 1], m2 = ep[e + 2], m3 = ep[e + 3];
                uint2 p0 = *(const uint2*)&hbin[(size_t)m0.x * 64 + hl * 4];
                uint2 p1 = *(const uint2*)&hbin[(size_t)m1.x * 64 + hl * 4];
                uint2 p2 = *(const uint2*)&hbin[(size_t)m2.x * 64 + hl * 4];
                uint2 p3 = *(const uint2*)&hbin[(size_t)m3.x * 64 + hl * 4];
                float w0 = __int_as_float(m0.y), w1 = __int_as_float(m1.y);
                float w2 = __int_as_float(m2.y), w3 = __int_as_float(m3.y);
                a0 += w0 * bf2f(p0.x & 0xffffu); a1 += w0 * bf2f(p0.x >> 16);
                a2 += w0 * bf2f(p0.y & 0xffffu); a3 += w0 * bf2f(p0.y >> 16);
                a0 += w1 * bf2f(p1.x & 0xffffu); a1 += w1 * bf2f(p1.x >> 16);
                a2 += w1 * bf2f(p1.y & 0xffffu); a3 += w1 * bf2f(p1.y >> 16);
                a0 += w2 * bf2f(p2.x & 0xffffu); a1 += w2 * bf2f(p2.x >> 16);
                a2 += w2 * bf2f(p2.y & 0xffffu); a3 += w2 * bf2f(p2.y >> 16);
                a0 += w3 * bf2f(p3.x & 0xffffu); a1 += w3 * bf2f(p3.x >> 16);
                a2 += w3 * bf2f(p3.y & 0xffffu); a3 += w3 * bf2f(p3.y >> 16);
            }
            for (; e < e1; ++e) {
                int2 m = ep[e];
                uint2 p = *(const uint2*)&hbin[(size_t)m.x * 64 + hl * 4];
                float w = __int_as_float(m.y);
                a0 += w * bf2f(p.x & 0xffffu); a1 += w * bf2f(p.x >> 16);
                a2 += w * bf2f(p.y & 0xffffu); a3 += w * bf2f(p.y >> 16);
            }
            uint2 hv = *(const uint2*)&h0b[(size_t)node * 64 + hl * 4];
            a0 += 0.1f * bf2f(hv.x & 0xffffu); a1 += 0.1f * bf2f(hv.x >> 16);   // w pre-scaled 0.9
            a2 += 0.1f * bf2f(hv.y & 0xffffu); a3 += 0.1f * bf2f(hv.y >> 16);
        }
        As[r * 65 + hl * 4 + 0] = a0;
        As[r * 65 + hl * 4 + 1] = a1;
        As[r * 65 + hl * 4 + 2] = a2;
        As[r * 65 + hl * 4 + 3] = a3;
    }
    __syncthreads();

    // GEMM: supp @ M (M streamed through L1 — 16 KB, fully resident)
    int cc = tid & 15, nc = tid >> 4;
    float acc[4][4] = {{0.f}};
#pragma unroll 8
    for (int k = 0; k < 64; ++k) {
        float4 b4 = *(const float4*)&M[k * 64 + cc * 4];
        float a0 = As[(nc * 4 + 0) * 65 + k];
        float a1 = As[(nc * 4 + 1) * 65 + k];
        float a2 = As[(nc * 4 + 2) * 65 + k];
        float a3 = As[(nc * 4 + 3) * 65 + k];
        acc[0][0] += a0 * b4.x; acc[0][1] += a0 * b4.y; acc[0][2] += a0 * b4.z; acc[0][3] += a0 * b4.w;
        acc[1][0] += a1 * b4.x; acc[1][1] += a1 * b4.y; acc[1][2] += a1 * b4.z; acc[1][3] += a1 * b4.w;
        acc[2][0] += a2 * b4.x; acc[2][1] += a2 * b4.y; acc[2][2] += a2 * b4.z; acc[2][3] += a2 * b4.w;
        acc[3][0] += a3 * b4.x; acc[3][1] += a3 * b4.y; acc[3][2] += a3 * b4.z; acc[3][3] += a3 * b4.w;
    }
#pragma unroll
    for (int i = 0; i < 4; ++i) {
        int gn = tile0 + nc * 4 + i;
        if (gn >= NN) continue;
        ushort4 ob;
        ob.x = f2bf(fmaxf(acc[i][0], 0.f));
        ob.y = f2bf(fmaxf(acc[i][1], 0.f));
        ob.z = f2bf(fmaxf(acc[i][2], 0.f));
        ob.w = f2bf(fmaxf(acc[i][3], 0.f));
        *(ushort4*)&hbout[(size_t)gn * 64 + cc * 4] = ob;
    }
}

// ---------------- final: out += 0.5*(max_l(h_l) @ head_w + head_b) ----------------
__global__ __launch_bounds__(256) void k_final(const unsigned short* __restrict__ h1,
                                               const unsigned short* __restrict__ h2,
                                               const unsigned short* __restrict__ h3,
                                               const unsigned short* __restrict__ h4,
                                               const float* __restrict__ hw,
                                               const float* __restrict__ hbias, float* __restrict__ out) {
    int wid = threadIdx.x >> 6, lane = threadIdx.x & 63;
    int node = blockIdx.x * 8 + wid * 2 + (lane >> 5);
    int ch = (lane & 31) * 2;
    size_t p = (size_t)node * 64 + ch;
    unsigned int a = *(const unsigned int*)&h1[p];
    unsigned int b = *(const unsigned int*)&h2[p];
    unsigned int c = *(const unsigned int*)&h3[p];
    unsigned int d = *(const unsigned int*)&h4[p];
    float m0 = fmaxf(fmaxf(bf2f(a & 0xffffu), bf2f(b & 0xffffu)),
                     fmaxf(bf2f(c & 0xffffu), bf2f(d & 0xffffu)));
    float m1 = fmaxf(fmaxf(bf2f(a >> 16), bf2f(b >> 16)),
                     fmaxf(bf2f(c >> 16), bf2f(d >> 16)));
    float v = m0 * hw[ch] + m1 * hw[ch + 1];
#pragma unroll
    for (int m = 16; m; m >>= 1) v += __shfl_xor(v, m);
    if ((lane & 31) == 0) out[node] = out[node] + 0.5f * (v + hbias[0]);
}

extern "C" void kernel_launch(void* const* d_in, const int* in_sizes, int n_in,
                              void* d_out, int out_size, void* d_ws, size_t ws_size,
                              hipStream_t stream) {
    const float* x      = (const float*)d_in[0];
    const float* ew     = (const float*)d_in[1];
    const float* proj_w = (const float*)d_in[2];
    const float* proj_b = (const float*)d_in[3];
    const float* gcn_w  = (const float*)d_in[4];
    const float* w1     = (const float*)d_in[5];
    const float* b1     = (const float*)d_in[6];
    const float* g1     = (const float*)d_in[7];
    const float* be1    = (const float*)d_in[8];
    const float* w2     = (const float*)d_in[9];
    const float* b2     = (const float*)d_in[10];
    const float* g2     = (const float*)d_in[11];
    const float* be2    = (const float*)d_in[12];
    const float* w3     = (const float*)d_in[13];
    const float* b3     = (const float*)d_in[14];
    const float* hw     = (const float*)d_in[15];
    const float* hb     = (const float*)d_in[16];
    const int*   ei     = (const int*)d_in[17];
    float* out = (float*)d_out;

    char* ws = (char*)d_ws;
    size_t off = 0;
    auto alloc = [&](size_t bytes) { size_t o = off; off += (bytes + 255) & ~(size_t)255; return o; };
    unsigned short* h0b = (unsigned short*)(ws + alloc((size_t)NN * 64 * 2));
    unsigned short* hl1 = (unsigned short*)(ws + alloc((size_t)NN * 64 * 2));
    unsigned short* hl2 = (unsigned short*)(ws + alloc((size_t)NN * 64 * 2));
    unsigned short* hl3 = (unsigned short*)(ws + alloc((size_t)NN * 64 * 2));
    unsigned short* hl4 = (unsigned short*)(ws + alloc((size_t)NN * 64 * 2));
    float* M       = (float*)(ws + alloc((size_t)4 * 64 * 64 * 4));
    int*   bcount  = (int*)(ws + alloc((size_t)NBUK * 4));
    int*   bstart  = (int*)(ws + alloc((size_t)(NBUK + 1) * 4));
    int*   bcursor = (int*)(ws + alloc((size_t)NBUK * 4));
    int*   row_ptr = (int*)(ws + alloc((size_t)(NN + 1) * 4));
    int2*  ep      = (int2*)(ws + alloc((size_t)NE * 8));
    int2*  ep2     = (int2*)(ws + alloc((size_t)NE * 8));

    const int* srcv = ei;
    const int* dstv = ei + NE;

    hipMemsetAsync(bcount, 0, (size_t)NBUK * 4, stream);

    k_bhist<<<NBLK, 256, 0, stream>>>(dstv, bcount);
    k_bscan<<<1, 256, 0, stream>>>(bcount, bstart, bcursor);
    k_bscatter<<<NBLK, 256, 0, stream>>>(srcv, dstv, ew, bcursor, ep);
    k_bsort<<<NBUK, 256, 0, stream>>>(ep, bstart, ep2, row_ptr);

    k_projmlp<<<NBUK, 256, 0, stream>>>(x, proj_w, proj_b, w1, b1, g1, be1,
                                        w2, b2, g2, be2, w3, b3, h0b, out);

    // theta_l = log(1/(l+1) + 1)
    k_mprep<<<64, 256, 0, stream>>>(gcn_w, M,
        make_float4(0.69314718055994531f, 0.40546510810816438f,
                    0.28768207245178085f, 0.22314355131420976f));

    k_layer<<<NBUK, 256, 0, stream>>>(ep2, row_ptr, h0b, h0b, M + 0 * 4096, hl1);
    k_layer<<<NBUK, 256, 0, stream>>>(ep2, row_ptr, hl1, h0b, M + 1 * 4096, hl2);
    k_layer<<<NBUK, 256, 0, stream>>>(ep2, row_ptr, hl2, h0b, M + 2 * 4096, hl3);
    k_layer<<<NBUK, 256, 0, stream>>>(ep2, row_ptr, hl3, h0b, M + 3 * 4096, hl4);

    k_final<<<NN / 8, 256, 0, stream>>>(hl1, hl2, hl3, hl4, hw, hb, out);
}

// Round 7
// 468.591 us; speedup vs baseline: 1.0325x; 1.0325x over previous
//
#include <hip/hip_runtime.h>

#define NN 100000
#define NE 1600000
#define DIN 128
#define HD 64
#define NBUK 1563          // ceil(100000/64) buckets of 64 nodes
#define EPB 2560           // edges per block in bucket build
#define NBLK 625           // 625 * 2560 = 1,600,000

__device__ __forceinline__ unsigned short f2bf(float f) {
    unsigned int u = __float_as_uint(f);
    u += 0x7fff + ((u >> 16) & 1);     // round-to-nearest-even
    return (unsigned short)(u >> 16);
}
__device__ __forceinline__ float bf2f(unsigned int lo16) {
    return __uint_as_float(lo16 << 16);
}

// ---------------- bucket histogram (LDS-aggregated) ----------------
__global__ __launch_bounds__(256) void k_bhist(const int* __restrict__ dst, int* __restrict__ bcount) {
    __shared__ int lh[NBUK];
    int tid = threadIdx.x;
    for (int b = tid; b < NBUK; b += 256) lh[b] = 0;
    __syncthreads();
    int base = blockIdx.x * EPB + tid;
#pragma unroll
    for (int i = 0; i < EPB / 256; ++i)
        atomicAdd(&lh[dst[base + i * 256] >> 6], 1);
    __syncthreads();
    for (int b = tid; b < NBUK; b += 256) {
        int c = lh[b];
        if (c) atomicAdd(&bcount[b], c);
    }
}

// ---------------- scan buckets -> bstart[0..NBUK], bcursor copy ----------------
__global__ __launch_bounds__(256) void k_bscan(const int* __restrict__ bcount, int* __restrict__ bstart,
                                               int* __restrict__ bcursor) {
    __shared__ int ts[256];
    int t = threadIdx.x;
    int vals[7];
    int s = 0;
#pragma unroll
    for (int j = 0; j < 7; ++j) {
        int ix = t * 7 + j;
        vals[j] = (ix < NBUK) ? bcount[ix] : 0;
        s += vals[j];
    }
    ts[t] = s;
    __syncthreads();
    for (int o = 1; o < 256; o <<= 1) {
        int xv = 0;
        if (t >= o) xv = ts[t - o];
        __syncthreads();
        ts[t] += xv;
        __syncthreads();
    }
    int run = (t == 0) ? 0 : ts[t - 1];
#pragma unroll
    for (int j = 0; j < 7; ++j) {
        int ix = t * 7 + j;
        if (ix <= NBUK) {
            bstart[ix] = run;
            if (ix < NBUK) bcursor[ix] = run;
        }
        run += vals[j];
    }
}

// ---------------- bucket scatter: block-aggregated reservation, L2-merged writes ----------------
// ep entry: { src | (row_in_bucket << 17),  0.9f * edge_weight }
__global__ __launch_bounds__(256) void k_bscatter(const int* __restrict__ src, const int* __restrict__ dst,
                                                  const float* __restrict__ ew, int* __restrict__ bcursor,
                                                  int2* __restrict__ ep) {
    __shared__ int lh[NBUK];
    __shared__ int gb[NBUK];
    int tid = threadIdx.x;
    for (int b = tid; b < NBUK; b += 256) lh[b] = 0;
    __syncthreads();
    int base = blockIdx.x * EPB + tid;
#pragma unroll
    for (int i = 0; i < EPB / 256; ++i)
        atomicAdd(&lh[dst[base + i * 256] >> 6], 1);
    __syncthreads();
    for (int b = tid; b < NBUK; b += 256) {
        int c = lh[b];
        if (c) gb[b] = atomicAdd(&bcursor[b], c);
    }
    __syncthreads();
#pragma unroll
    for (int i = 0; i < EPB / 256; ++i) {
        int e = base + i * 256;
        int d = dst[e];
        int pos = atomicAdd(&gb[d >> 6], 1);
        ep[pos] = make_int2(src[e] | ((d & 63) << 17), __float_as_int(0.9f * ew[e]));
    }
}

// ---------------- per-bucket node sort: ep -> ep2 (CSR order) + row_ptr ----------------
__global__ __launch_bounds__(256) void k_bsort(const int2* __restrict__ ep, const int* __restrict__ bstart,
                                               int2* __restrict__ ep2, int* __restrict__ row_ptr) {
    __shared__ int cnt64[64];
    __shared__ int cur64[64];
    int b = blockIdx.x;
    int tid = threadIdx.x;
    if (tid < 64) cnt64[tid] = 0;
    __syncthreads();
    int e0 = bstart[b], e1 = bstart[b + 1];
    for (int e = e0 + tid; e < e1; e += 256)
        atomicAdd(&cnt64[(ep[e].x >> 17) & 63], 1);
    __syncthreads();
    if (tid == 0) {
        int run = e0;
        for (int r = 0; r < 64; ++r) {
            int node = b * 64 + r;
            cur64[r] = run;
            if (node <= NN) row_ptr[node] = run;
            run += cnt64[r];
        }
    }
    __syncthreads();
    for (int e = e0 + tid; e < e1; e += 256) {
        int2 m = ep[e];
        int r = (m.x >> 17) & 63;
        int pos = atomicAdd(&cur64[r], 1);
        ep2[pos] = make_int2(m.x & 0x1FFFF, m.y);
    }
    if (b == NBUK - 1 && tid == 0) row_ptr[NN] = e1;
}

// ---------------- M_l = theta*W_l + (1-theta)*I ----------------
__global__ __launch_bounds__(256) void k_mprep(const float* __restrict__ gw, float* __restrict__ M, float4 th) {
    int idx = blockIdx.x * 256 + threadIdx.x;   // < 4*64*64
    int l = idx >> 12;
    int k = (idx >> 6) & 63;
    int c = idx & 63;
    float theta = (l == 0) ? th.x : (l == 1) ? th.y : (l == 2) ? th.z : th.w;
    float m = theta * gw[idx];
    if (k == c) m += (1.f - theta);
    M[idx] = m;
}

// ---------------- fused proj + MLP branch: one pass over x (R5 form: LDS-staged Bs) ----------------
__global__ __launch_bounds__(256) void k_projmlp(const float* __restrict__ x,
        const float* __restrict__ pW, const float* __restrict__ pb,
        const float* __restrict__ W1, const float* __restrict__ b1,
        const float* __restrict__ g1, const float* __restrict__ be1,
        const float* __restrict__ W2, const float* __restrict__ b2,
        const float* __restrict__ g2, const float* __restrict__ be2,
        const float* __restrict__ w3, const float* __restrict__ b3,
        unsigned short* __restrict__ h0b, float* __restrict__ out) {
    __shared__ float As[64 * 65];
    __shared__ float Bs1[64 * 64];
    __shared__ float Bs2[64 * 64];
    float2* red = (float2*)Bs2;          // alias: Bs2 is free after the k-loop
    int tid = threadIdx.x;
    int cc = tid & 15, nc = tid >> 4;
    int tile0 = blockIdx.x * 64;
    float accP[4][4] = {{0.f}};
    float accM[4][4] = {{0.f}};
    for (int kc = 0; kc < DIN; kc += 64) {
        __syncthreads();
#pragma unroll
        for (int it = 0; it < 4; ++it) {
            int idx = tid + it * 256;
            int r = idx >> 4, q = (idx & 15) * 4;
            int gn = tile0 + r;
            float4 v = make_float4(0.f, 0.f, 0.f, 0.f);
            if (gn < NN) v = *(const float4*)&x[(size_t)gn * DIN + kc + q];
            As[r * 65 + q + 0] = v.x; As[r * 65 + q + 1] = v.y;
            As[r * 65 + q + 2] = v.z; As[r * 65 + q + 3] = v.w;
            *(float4*)&Bs1[r * 64 + q] = *(const float4*)&pW[(size_t)(kc + r) * 64 + q];
            *(float4*)&Bs2[r * 64 + q] = *(const float4*)&W1[(size_t)(kc + r) * 64 + q];
        }
        __syncthreads();
#pragma unroll 4
        for (int k = 0; k < 64; ++k) {
            float4 bp = *(const float4*)&Bs1[k * 64 + cc * 4];
            float4 bm = *(const float4*)&Bs2[k * 64 + cc * 4];
            float a0 = As[(nc * 4 + 0) * 65 + k];
            float a1 = As[(nc * 4 + 1) * 65 + k];
            float a2 = As[(nc * 4 + 2) * 65 + k];
            float a3 = As[(nc * 4 + 3) * 65 + k];
            accP[0][0] += a0 * bp.x; accP[0][1] += a0 * bp.y; accP[0][2] += a0 * bp.z; accP[0][3] += a0 * bp.w;
            accP[1][0] += a1 * bp.x; accP[1][1] += a1 * bp.y; accP[1][2] += a1 * bp.z; accP[1][3] += a1 * bp.w;
            accP[2][0] += a2 * bp.x; accP[2][1] += a2 * bp.y; accP[2][2] += a2 * bp.z; accP[2][3] += a2 * bp.w;
            accP[3][0] += a3 * bp.x; accP[3][1] += a3 * bp.y; accP[3][2] += a3 * bp.z; accP[3][3] += a3 * bp.w;
            accM[0][0] += a0 * bm.x; accM[0][1] += a0 * bm.y; accM[0][2] += a0 * bm.z; accM[0][3] += a0 * bm.w;
            accM[1][0] += a1 * bm.x; accM[1][1] += a1 * bm.y; accM[1][2] += a1 * bm.z; accM[1][3] += a1 * bm.w;
            accM[2][0] += a2 * bm.x; accM[2][1] += a2 * bm.y; accM[2][2] += a2 * bm.z; accM[2][3] += a2 * bm.w;
            accM[3][0] += a3 * bm.x; accM[3][1] += a3 * bm.y; accM[3][2] += a3 * bm.z; accM[3][3] += a3 * bm.w;
        }
    }
    __syncthreads();   // k-loop reads of As/Bs1/Bs2 done
    // proj epilogue -> h0b (bf16)
#pragma unroll
    for (int i = 0; i < 4; ++i) {
        int gn = tile0 + nc * 4 + i;
        if (gn < NN) {
            ushort4 ob;
            ob.x = f2bf(accP[i][0] + pb[cc * 4 + 0]);
            ob.y = f2bf(accP[i][1] + pb[cc * 4 + 1]);
            ob.z = f2bf(accP[i][2] + pb[cc * 4 + 2]);
            ob.w = f2bf(accP[i][3] + pb[cc * 4 + 3]);
            *(ushort4*)&h0b[(size_t)gn * 64 + cc * 4] = ob;
        }
    }
    // mlp stats1 (bias folded); red aliases Bs2
    float vals[4][4];
#pragma unroll
    for (int i = 0; i < 4; ++i) {
        float s = 0.f, q = 0.f;
#pragma unroll
        for (int j = 0; j < 4; ++j) {
            float v = accM[i][j] + b1[cc * 4 + j];
            vals[i][j] = v; s += v; q += v * v;
        }
        red[(nc * 4 + i) * 17 + cc] = make_float2(s, q);
    }
    // stage W2 into Bs1
#pragma unroll
    for (int it = 0; it < 4; ++it) {
        int idx = tid + it * 256;
        int k = idx >> 4, q = (idx & 15) * 4;
        *(float4*)&Bs1[k * 64 + q] = *(const float4*)&W2[(size_t)k * 64 + q];
    }
    __syncthreads();
    // LN1 + relu -> m1 into As
#pragma unroll
    for (int i = 0; i < 4; ++i) {
        int r = nc * 4 + i;
        float S = 0.f, Q = 0.f;
#pragma unroll
        for (int j = 0; j < 16; ++j) { float2 f = red[r * 17 + j]; S += f.x; Q += f.y; }
        float mu = S * (1.f / 64.f);
        float var = Q * (1.f / 64.f) - mu * mu;
        float rs = rsqrtf(var + 1e-5f);
#pragma unroll
        for (int j = 0; j < 4; ++j) {
            int c = cc * 4 + j;
            float m = (vals[i][j] - mu) * rs * g1[c] + be1[c];
            As[r * 65 + c] = fmaxf(m, 0.f);
        }
    }
    __syncthreads();
    // GEMM2: m1 @ W2
    float acc2[4][4] = {{0.f}};
#pragma unroll 8
    for (int k = 0; k < 64; ++k) {
        float4 b4 = *(const float4*)&Bs1[k * 64 + cc * 4];
        float a0 = As[(nc * 4 + 0) * 65 + k];
        float a1 = As[(nc * 4 + 1) * 65 + k];
        float a2 = As[(nc * 4 + 2) * 65 + k];
        float a3 = As[(nc * 4 + 3) * 65 + k];
        acc2[0][0] += a0 * b4.x; acc2[0][1] += a0 * b4.y; acc2[0][2] += a0 * b4.z; acc2[0][3] += a0 * b4.w;
        acc2[1][0] += a1 * b4.x; acc2[1][1] += a1 * b4.y; acc2[1][2] += a1 * b4.z; acc2[1][3] += a1 * b4.w;
        acc2[2][0] += a2 * b4.x; acc2[2][1] += a2 * b4.y; acc2[2][2] += a2 * b4.z; acc2[2][3] += a2 * b4.w;
        acc2[3][0] += a3 * b4.x; acc2[3][1] += a3 * b4.y; acc2[3][2] += a3 * b4.z; acc2[3][3] += a3 * b4.w;
    }
    __syncthreads();
    // stats2
#pragma unroll
    for (int i = 0; i < 4; ++i) {
        float s = 0.f, q = 0.f;
#pragma unroll
        for (int j = 0; j < 4; ++j) {
            float v = acc2[i][j] + b2[cc * 4 + j];
            vals[i][j] = v; s += v; q += v * v;
        }
        red[(nc * 4 + i) * 17 + cc] = make_float2(s, q);
    }
    __syncthreads();
    // LN2 + relu + dot w3
    float part[4];
#pragma unroll
    for (int i = 0; i < 4; ++i) {
        int r = nc * 4 + i;
        float S = 0.f, Q = 0.f;
#pragma unroll
        for (int j = 0; j < 16; ++j) { float2 f = red[r * 17 + j]; S += f.x; Q += f.y; }
        float mu = S * (1.f / 64.f);
        float var = Q * (1.f / 64.f) - mu * mu;
        float rs = rsqrtf(var + 1e-5f);
        float p = 0.f;
#pragma unroll
        for (int j = 0; j < 4; ++j) {
            int c = cc * 4 + j;
            float m = fmaxf((vals[i][j] - mu) * rs * g2[c] + be2[c], 0.f);
            p += m * w3[c];
        }
        part[i] = p;
    }
    __syncthreads();
#pragma unroll
    for (int i = 0; i < 4; ++i) red[(nc * 4 + i) * 17 + cc] = make_float2(part[i], 0.f);
    __syncthreads();
    if (tid < 64) {
        float S = 0.f;
#pragma unroll
        for (int j = 0; j < 16; ++j) S += red[tid * 17 + j].x;
        int gn = tile0 + tid;
        if (gn < NN) out[gn] = 0.5f * (S + b3[0]);
    }
}

// ---------------- fused layer: CSR spmm (reg accum, 16 lanes/node, 8-edge unroll) + GEMM(M from L1) ----------------
__global__ __launch_bounds__(256) void k_layer(const int2* __restrict__ ep, const int* __restrict__ row_ptr,
                                               const unsigned short* __restrict__ hbin,   // bf16 h prev
                                               const unsigned short* __restrict__ h0b,    // bf16 h0
                                               const float* __restrict__ M,               // 64x64
                                               unsigned short* __restrict__ hbout) {      // bf16 h out
    __shared__ float As[64 * 65];
    int tid = threadIdx.x;
    int wid = tid >> 6, lane = tid & 63;
    int g = lane >> 4, hl = lane & 15;       // group g of 16 lanes; lane covers channels hl*4..hl*4+3
    int tile0 = blockIdx.x * 64;

    // spmm: wave covers 16 rows, 4 concurrent groups x 8-edge unroll -> 32 lines in flight/wave
#pragma unroll 1
    for (int i = 0; i < 4; ++i) {
        int r = wid * 16 + i * 4 + g;
        int node = tile0 + r;
        float a0 = 0.f, a1 = 0.f, a2 = 0.f, a3 = 0.f;
        if (node < NN) {
            int e = row_ptr[node], e1 = row_ptr[node + 1];
            for (; e + 8 <= e1; e += 8) {
                int2 m[8];
#pragma unroll
                for (int j = 0; j < 8; ++j) m[j] = ep[e + j];
                uint2 p[8];
#pragma unroll
                for (int j = 0; j < 8; ++j)
                    p[j] = *(const uint2*)&hbin[(size_t)m[j].x * 64 + hl * 4];
#pragma unroll
                for (int j = 0; j < 8; ++j) {
                    float w = __int_as_float(m[j].y);
                    a0 += w * bf2f(p[j].x & 0xffffu); a1 += w * bf2f(p[j].x >> 16);
                    a2 += w * bf2f(p[j].y & 0xffffu); a3 += w * bf2f(p[j].y >> 16);
                }
            }
            if (e + 4 <= e1) {
                int2 m[4];
#pragma unroll
                for (int j = 0; j < 4; ++j) m[j] = ep[e + j];
                uint2 p[4];
#pragma unroll
                for (int j = 0; j < 4; ++j)
                    p[j] = *(const uint2*)&hbin[(size_t)m[j].x * 64 + hl * 4];
#pragma unroll
                for (int j = 0; j < 4; ++j) {
                    float w = __int_as_float(m[j].y);
                    a0 += w * bf2f(p[j].x & 0xffffu); a1 += w * bf2f(p[j].x >> 16);
                    a2 += w * bf2f(p[j].y & 0xffffu); a3 += w * bf2f(p[j].y >> 16);
                }
                e += 4;
            }
            for (; e < e1; ++e) {
                int2 m = ep[e];
                uint2 p = *(const uint2*)&hbin[(size_t)m.x * 64 + hl * 4];
                float w = __int_as_float(m.y);
                a0 += w * bf2f(p.x & 0xffffu); a1 += w * bf2f(p.x >> 16);
                a2 += w * bf2f(p.y & 0xffffu); a3 += w * bf2f(p.y >> 16);
            }
            uint2 hv = *(const uint2*)&h0b[(size_t)node * 64 + hl * 4];
            a0 += 0.1f * bf2f(hv.x & 0xffffu); a1 += 0.1f * bf2f(hv.x >> 16);   // w pre-scaled 0.9
            a2 += 0.1f * bf2f(hv.y & 0xffffu); a3 += 0.1f * bf2f(hv.y >> 16);
        }
        As[r * 65 + hl * 4 + 0] = a0;
        As[r * 65 + hl * 4 + 1] = a1;
        As[r * 65 + hl * 4 + 2] = a2;
        As[r * 65 + hl * 4 + 3] = a3;
    }
    __syncthreads();

    // GEMM: supp @ M (M streamed through L1 — 16 KB, fully resident)
    int cc = tid & 15, nc = tid >> 4;
    float acc[4][4] = {{0.f}};
#pragma unroll 8
    for (int k = 0; k < 64; ++k) {
        float4 b4 = *(const float4*)&M[k * 64 + cc * 4];
        float a0 = As[(nc * 4 + 0) * 65 + k];
        float a1 = As[(nc * 4 + 1) * 65 + k];
        float a2 = As[(nc * 4 + 2) * 65 + k];
        float a3 = As[(nc * 4 + 3) * 65 + k];
        acc[0][0] += a0 * b4.x; acc[0][1] += a0 * b4.y; acc[0][2] += a0 * b4.z; acc[0][3] += a0 * b4.w;
        acc[1][0] += a1 * b4.x; acc[1][1] += a1 * b4.y; acc[1][2] += a1 * b4.z; acc[1][3] += a1 * b4.w;
        acc[2][0] += a2 * b4.x; acc[2][1] += a2 * b4.y; acc[2][2] += a2 * b4.z; acc[2][3] += a2 * b4.w;
        acc[3][0] += a3 * b4.x; acc[3][1] += a3 * b4.y; acc[3][2] += a3 * b4.z; acc[3][3] += a3 * b4.w;
    }
#pragma unroll
    for (int i = 0; i < 4; ++i) {
        int gn = tile0 + nc * 4 + i;
        if (gn >= NN) continue;
        ushort4 ob;
        ob.x = f2bf(fmaxf(acc[i][0], 0.f));
        ob.y = f2bf(fmaxf(acc[i][1], 0.f));
        ob.z = f2bf(fmaxf(acc[i][2], 0.f));
        ob.w = f2bf(fmaxf(acc[i][3], 0.f));
        *(ushort4*)&hbout[(size_t)gn * 64 + cc * 4] = ob;
    }
}

// ---------------- final: out += 0.5*(max_l(h_l) @ head_w + head_b) ----------------
__global__ __launch_bounds__(256) void k_final(const unsigned short* __restrict__ h1,
                                               const unsigned short* __restrict__ h2,
                                               const unsigned short* __restrict__ h3,
                                               const unsigned short* __restrict__ h4,
                                               const float* __restrict__ hw,
                                               const float* __restrict__ hbias, float* __restrict__ out) {
    int wid = threadIdx.x >> 6, lane = threadIdx.x & 63;
    int node = blockIdx.x * 8 + wid * 2 + (lane >> 5);
    int ch = (lane & 31) * 2;
    size_t p = (size_t)node * 64 + ch;
    unsigned int a = *(const unsigned int*)&h1[p];
    unsigned int b = *(const unsigned int*)&h2[p];
    unsigned int c = *(const unsigned int*)&h3[p];
    unsigned int d = *(const unsigned int*)&h4[p];
    float m0 = fmaxf(fmaxf(bf2f(a & 0xffffu), bf2f(b & 0xffffu)),
                     fmaxf(bf2f(c & 0xffffu), bf2f(d & 0xffffu)));
    float m1 = fmaxf(fmaxf(bf2f(a >> 16), bf2f(b >> 16)),
                     fmaxf(bf2f(c >> 16), bf2f(d >> 16)));
    float v = m0 * hw[ch] + m1 * hw[ch + 1];
#pragma unroll
    for (int m = 16; m; m >>= 1) v += __shfl_xor(v, m);
    if ((lane & 31) == 0) out[node] = out[node] + 0.5f * (v + hbias[0]);
}

extern "C" void kernel_launch(void* const* d_in, const int* in_sizes, int n_in,
                              void* d_out, int out_size, void* d_ws, size_t ws_size,
                              hipStream_t stream) {
    const float* x      = (const float*)d_in[0];
    const float* ew     = (const float*)d_in[1];
    const float* proj_w = (const float*)d_in[2];
    const float* proj_b = (const float*)d_in[3];
    const float* gcn_w  = (const float*)d_in[4];
    const float* w1     = (const float*)d_in[5];
    const float* b1     = (const float*)d_in[6];
    const float* g1     = (const float*)d_in[7];
    const float* be1    = (const float*)d_in[8];
    const float* w2     = (const float*)d_in[9];
    const float* b2     = (const float*)d_in[10];
    const float* g2     = (const float*)d_in[11];
    const float* be2    = (const float*)d_in[12];
    const float* w3     = (const float*)d_in[13];
    const float* b3     = (const float*)d_in[14];
    const float* hw     = (const float*)d_in[15];
    const float* hb     = (const float*)d_in[16];
    const int*   ei     = (const int*)d_in[17];
    float* out = (float*)d_out;

    char* ws = (char*)d_ws;
    size_t off = 0;
    auto alloc = [&](size_t bytes) { size_t o = off; off += (bytes + 255) & ~(size_t)255; return o; };
    unsigned short* h0b = (unsigned short*)(ws + alloc((size_t)NN * 64 * 2));
    unsigned short* hl1 = (unsigned short*)(ws + alloc((size_t)NN * 64 * 2));
    unsigned short* hl2 = (unsigned short*)(ws + alloc((size_t)NN * 64 * 2));
    unsigned short* hl3 = (unsigned short*)(ws + alloc((size_t)NN * 64 * 2));
    unsigned short* hl4 = (unsigned short*)(ws + alloc((size_t)NN * 64 * 2));
    float* M       = (float*)(ws + alloc((size_t)4 * 64 * 64 * 4));
    int*   bcount  = (int*)(ws + alloc((size_t)NBUK * 4));
    int*   bstart  = (int*)(ws + alloc((size_t)(NBUK + 1) * 4));
    int*   bcursor = (int*)(ws + alloc((size_t)NBUK * 4));
    int*   row_ptr = (int*)(ws + alloc((size_t)(NN + 1) * 4));
    int2*  ep      = (int2*)(ws + alloc((size_t)NE * 8));
    int2*  ep2     = (int2*)(ws + alloc((size_t)NE * 8));

    const int* srcv = ei;
    const int* dstv = ei + NE;

    hipMemsetAsync(bcount, 0, (size_t)NBUK * 4, stream);

    k_bhist<<<NBLK, 256, 0, stream>>>(dstv, bcount);
    k_bscan<<<1, 256, 0, stream>>>(bcount, bstart, bcursor);
    k_bscatter<<<NBLK, 256, 0, stream>>>(srcv, dstv, ew, bcursor, ep);
    k_bsort<<<NBUK, 256, 0, stream>>>(ep, bstart, ep2, row_ptr);

    k_projmlp<<<NBUK, 256, 0, stream>>>(x, proj_w, proj_b, w1, b1, g1, be1,
                                        w2, b2, g2, be2, w3, b3, h0b, out);

    // theta_l = log(1/(l+1) + 1)
    k_mprep<<<64, 256, 0, stream>>>(gcn_w, M,
        make_float4(0.69314718055994531f, 0.40546510810816438f,
                    0.28768207245178085f, 0.22314355131420976f));

    k_layer<<<NBUK, 256, 0, stream>>>(ep2, row_ptr, h0b, h0b, M + 0 * 4096, hl1);
    k_layer<<<NBUK, 256, 0, stream>>>(ep2, row_ptr, hl1, h0b, M + 1 * 4096, hl2);
    k_layer<<<NBUK, 256, 0, stream>>>(ep2, row_ptr, hl2, h0b, M + 2 * 4096, hl3);
    k_layer<<<NBUK, 256, 0, stream>>>(ep2, row_ptr, hl3, h0b, M + 3 * 4096, hl4);

    k_final<<<NN / 8, 256, 0, stream>>>(hl1, hl2, hl3, hl4, hw, hb, out);
}